// Round 1
// 160.499 us; speedup vs baseline: 1.0212x; 1.0212x over previous
//
#include <hip/hip_runtime.h>

#define B_DIM   4096
#define IN_DIM  4096
#define OUT_DIM 4096

typedef float floatx4 __attribute__((ext_vector_type(4)));

// Kernel A: row sums for BOTH matrices as pure-read streams.
//   blocks [0, 1024):    wb[o] = bias[o] * sum_i weight[o,i]   (o = blk*4+wave)
//   blocks [1024, 2048): xs[b] = sum_i input[b,i]              (b = (blk-1024)*4+wave)
// One wave per row, 16x dwordx4 nontemporal loads per lane (rows streamed once,
// don't pollute L1/L2). No __syncthreads anywhere (per-wave row ownership).
__global__ __launch_bounds__(256) void sums_kernel(
    const float* __restrict__ input, const float* __restrict__ weight,
    const float* __restrict__ bias, float* __restrict__ wb,
    float* __restrict__ xs)
{
    const int wave = threadIdx.x >> 6;
    const int lane = threadIdx.x & 63;
    const bool is_w = (blockIdx.x < (OUT_DIM / 4));
    const int row  = (is_w ? blockIdx.x : (blockIdx.x - OUT_DIM / 4)) * 4 + wave;
    const float* __restrict__ base = is_w ? weight : input;

    const floatx4* src4 = (const floatx4*)(base + (size_t)row * IN_DIM);

    float s0 = 0.f, s1 = 0.f, s2 = 0.f, s3 = 0.f;
    #pragma unroll
    for (int k = 0; k < 16; k += 4) {
        floatx4 v0 = __builtin_nontemporal_load(&src4[lane + (k + 0) * 64]);
        floatx4 v1 = __builtin_nontemporal_load(&src4[lane + (k + 1) * 64]);
        floatx4 v2 = __builtin_nontemporal_load(&src4[lane + (k + 2) * 64]);
        floatx4 v3 = __builtin_nontemporal_load(&src4[lane + (k + 3) * 64]);
        s0 += (v0.x + v0.y) + (v0.z + v0.w);
        s1 += (v1.x + v1.y) + (v1.z + v1.w);
        s2 += (v2.x + v2.y) + (v2.z + v2.w);
        s3 += (v3.x + v3.y) + (v3.z + v3.w);
    }
    float s = (s0 + s1) + (s2 + s3);

    #pragma unroll
    for (int off = 32; off > 0; off >>= 1)
        s += __shfl_down(s, off, 64);

    if (lane == 0) {
        if (is_w) wb[row] = s * bias[row];
        else      xs[row] = s;
    }
}

// Kernel B: pure-write stream. out[b,o] = fma(xs[b], bias[o], wb[o]).
// 4 consecutive b-rows per block: bias/wb (L2-resident, 16 KB each) are read
// once per block into registers and reused across the 4 rows; 16 nontemporal
// dwordx4 stores per thread, coalesced per row.
__global__ __launch_bounds__(256) void write_kernel(
    const float* __restrict__ bias, const float* __restrict__ wb,
    const float* __restrict__ xs, float* __restrict__ out)
{
    const int t  = threadIdx.x;
    const int b0 = blockIdx.x * 4;

    const float x0 = xs[b0 + 0];
    const float x1 = xs[b0 + 1];
    const float x2 = xs[b0 + 2];
    const float x3 = xs[b0 + 3];

    const floatx4* bias4 = (const floatx4*)bias;
    const floatx4* wb4   = (const floatx4*)wb;
    floatx4* out4 = (floatx4*)out;

    #pragma unroll
    for (int k = 0; k < 4; ++k) {
        const int i = t + k * 256;
        const floatx4 bi = bias4[i];
        const floatx4 w  = wb4[i];
        floatx4 r0, r1, r2, r3;
        r0.x = fmaf(x0, bi.x, w.x); r0.y = fmaf(x0, bi.y, w.y);
        r0.z = fmaf(x0, bi.z, w.z); r0.w = fmaf(x0, bi.w, w.w);
        r1.x = fmaf(x1, bi.x, w.x); r1.y = fmaf(x1, bi.y, w.y);
        r1.z = fmaf(x1, bi.z, w.z); r1.w = fmaf(x1, bi.w, w.w);
        r2.x = fmaf(x2, bi.x, w.x); r2.y = fmaf(x2, bi.y, w.y);
        r2.z = fmaf(x2, bi.z, w.z); r2.w = fmaf(x2, bi.w, w.w);
        r3.x = fmaf(x3, bi.x, w.x); r3.y = fmaf(x3, bi.y, w.y);
        r3.z = fmaf(x3, bi.z, w.z); r3.w = fmaf(x3, bi.w, w.w);
        __builtin_nontemporal_store(r0, &out4[(size_t)(b0 + 0) * (OUT_DIM / 4) + i]);
        __builtin_nontemporal_store(r1, &out4[(size_t)(b0 + 1) * (OUT_DIM / 4) + i]);
        __builtin_nontemporal_store(r2, &out4[(size_t)(b0 + 2) * (OUT_DIM / 4) + i]);
        __builtin_nontemporal_store(r3, &out4[(size_t)(b0 + 3) * (OUT_DIM / 4) + i]);
    }
}

extern "C" void kernel_launch(void* const* d_in, const int* in_sizes, int n_in,
                              void* d_out, int out_size, void* d_ws, size_t ws_size,
                              hipStream_t stream) {
    const float* input  = (const float*)d_in[0];
    const float* weight = (const float*)d_in[1];
    const float* bias   = (const float*)d_in[2];
    float* out = (float*)d_out;
    float* wb  = (float*)d_ws;            // 4096 floats: bias[o] * w_sum[o]
    float* xs  = (float*)d_ws + OUT_DIM;  // 4096 floats: x_sum[b]

    sums_kernel<<<2 * (OUT_DIM / 4), 256, 0, stream>>>(input, weight, bias, wb, xs);
    write_kernel<<<B_DIM / 4, 256, 0, stream>>>(bias, wb, xs, out);
}